// Round 15
// baseline (88.100 us; speedup 1.0000x reference)
//
#include <hip/hip_runtime.h>
#include <cstdint>
#include <cstddef>

typedef _Float16 f16x8 __attribute__((ext_vector_type(8)));
typedef _Float16 f16x4 __attribute__((ext_vector_type(4)));
typedef float    f32x4 __attribute__((ext_vector_type(4)));

#define MFMA16(a,b,c) __builtin_amdgcn_mfma_f32_16x16x32_f16((a),(b),(c),0,0,0)

// ws layout (halfs) — weights in 16x16-MFMA fragment-linear order (R12/R13-verified):
//   W1F  [15][4ot][8kk][64][8] @0       (245760)
//   W16F [4ot][12kk][64][8]    @245760  (24576)   sp=32kk+8(l>>4)+j; x col=1808+sp; zero sp<12 or sp>=368
//   W2F  [16t][8kk][64][8]     @270336  (65536)
//   W3F  [17t][8kk][64][8]     @335872  (69632)   o>=260 zero
__global__ void tea_prep(const float* __restrict__ W1, const float* __restrict__ W16,
                         const float* __restrict__ W2, const float* __restrict__ W3,
                         _Float16* __restrict__ ws)
{
    int i = blockIdx.x * blockDim.x + threadIdx.x;
    if (i < 245760) {
        int win = i >> 14, t = i & 16383;
        int ot = t >> 12, kk = (t >> 9) & 7, l = (t >> 3) & 63, j = t & 7;
        int o = 16 * ot + (l & 15);
        int s = 32 * kk + 8 * (l >> 4) + j;
        ws[i] = (_Float16)W1[(win * 256 + s) * 64 + o];
    } else if (i < 270336) {
        int t = i - 245760;
        int ot = t / 6144, t2 = t % 6144;
        int kk = t2 >> 9, l = (t2 >> 3) & 63, j = t2 & 7;
        int o = 16 * ot + (l & 15);
        int sp = 32 * kk + 8 * (l >> 4) + j;
        ws[i] = (_Float16)((sp >= 12 && sp < 368) ? W16[(sp - 12) * 64 + o] : 0.f);
    } else if (i < 335872) {
        int t = i - 270336;
        int q2 = t >> 12, kk = (t >> 9) & 7, l = (t >> 3) & 63, j = t & 7;
        int og = 16 * q2 + (l & 15);
        int g = q2 >> 2, o2 = og - 64 * g;
        int s = 32 * kk + 8 * (l >> 4) + j;
        ws[i] = (_Float16)W2[(g * 256 + s) * 64 + o2];
    } else if (i < 405504) {
        int t = i - 335872;
        int tt = t >> 12, kk = (t >> 9) & 7, l = (t >> 3) & 63, j = t & 7;
        int o = 16 * tt + (l & 15);
        int s = 32 * kk + 8 * (l >> 4) + j;
        ws[i] = (_Float16)((o < 260) ? W3[s * 260 + o] : 0.f);
    }
}

// DMA-pipelined fused kernel (R13 + counted vmcnt + 7-slot ring + group-wise y).
// 512 blocks x 32 rows, 1024 threads (16 waves), 1 block/CU.
// LDS sh[74240] halfs = 148480 B:
//   ring: 7 slots x [32 rows][512 B] fp32 chunks, bytes [0, 114688)
//         (source-XOR-swizzled: byte-in-row ^= (row&7)<<4, applied on DMA src AND reads)
//   ygrp: f16 [32][264], halfs [57344, 65792)   current group's y (4 windows x 64)
//   zsm : f16 [32][264], halfs [65792, 74240)
//   ps  : f32 [17][32][10], bytes [0, 21760)    alias ring (written in l3; ring dead)
__global__ __launch_bounds__(1024, 4)
void tea_dma(const float* __restrict__ x,
             const float* __restrict__ b1,  const float* __restrict__ b16,
             const float* __restrict__ b2,  const float* __restrict__ b3,
             const _Float16* __restrict__ ws, float* __restrict__ out)
{
    __shared__ _Float16 sh[74240];
    char* shb = (char*)sh;

    const int tid = threadIdx.x;
    const int bid = blockIdx.x;
    const int wg  = (bid & 7) * 64 + (bid >> 3);      // bijective XCD swizzle (512%8==0)
    const int q = tid >> 6, l = tid & 63, r = l & 15, kg = l >> 4;

    const char* xb = (const char*)(x + (size_t)wg * 32 * 2176);

    // one global_load_lds per wave per chunk: wave q covers chunk rows 2q, 2q+1.
    auto issue = [&](int c) {
        int row = 2 * q + (l >> 5);
        int colphys = (l & 31) * 16;
        int collog = colphys ^ ((row & 7) << 4);      // inverse-swizzle the SOURCE
        const void* src = xb + (size_t)row * 8704 + (size_t)c * 512 + collog;
        void* dst = shb + (c % 7) * 16384 + q * 1024; // wave-uniform, linear
        __builtin_amdgcn_global_load_lds(
            (const __attribute__((address_space(1))) void*)src,
            (__attribute__((address_space(3))) void*)dst, 16, 0, 0);
    };

    // counted-vmcnt pass tops: older chunks proven delivered, newer stay in flight
#define PASSTOP4() do { \
    asm volatile("s_waitcnt vmcnt(4) lgkmcnt(0)" ::: "memory"); \
    __builtin_amdgcn_s_barrier(); \
    __builtin_amdgcn_sched_barrier(0); } while (0)
#define PASSTOP2() do { \
    asm volatile("s_waitcnt vmcnt(2) lgkmcnt(0)" ::: "memory"); \
    __builtin_amdgcn_s_barrier(); \
    __builtin_amdgcn_sched_barrier(0); } while (0)
#define PASSTOP0() do { \
    asm volatile("s_waitcnt vmcnt(0) lgkmcnt(0)" ::: "memory"); \
    __builtin_amdgcn_s_barrier(); \
    __builtin_amdgcn_sched_barrier(0); } while (0)
#define BARL() do { \
    asm volatile("s_waitcnt lgkmcnt(0)" ::: "memory"); \
    __builtin_amdgcn_s_barrier(); \
    __builtin_amdgcn_sched_barrier(0); } while (0)

    // B-frag from ring: 8 fp32 at (row, cols) of chunk in slotbyte (read-side XOR)
    auto bfrag = [&](int slotbyte, int rowloc, int colb) -> f16x8 {
        int swz = (rowloc & 7) << 4;
        f32x4 u = *(const f32x4*)(shb + slotbyte + rowloc * 512 + (colb ^ swz));
        f32x4 v = *(const f32x4*)(shb + slotbyte + rowloc * 512 + ((colb + 16) ^ swz));
        f16x8 B;
        B[0] = (_Float16)u[0]; B[1] = (_Float16)u[1]; B[2] = (_Float16)u[2]; B[3] = (_Float16)u[3];
        B[4] = (_Float16)v[0]; B[5] = (_Float16)v[1]; B[6] = (_Float16)v[2]; B[7] = (_Float16)v[3];
        return B;
    };

    // window compute: this wave = (win, rh, ot=q&3); 16 rows x 16 outs, K=256
    auto wincomp = [&](int win, int rh, const float* bp) {
        const _Float16* A = ws + win * 16384 + (q & 3) * 4096;
        const int rowloc = 16 * rh + r;
        f32x4 acc = {0.f, 0.f, 0.f, 0.f};
        #pragma unroll
        for (int kk = 0; kk < 8; ++kk) {
            int slotb = ((win + (kk >> 2)) % 7) * 16384;
            int colb = 128 * (kk & 3) + 32 * kg;
            f16x8 B  = bfrag(slotb, rowloc, colb);
            f16x8 Af = *(const f16x8*)(A + kk * 512 + l * 8);
            acc = MFMA16(Af, B, acc);
        }
        float4 bv = *(const float4*)(bp + 16 * (q & 3) + 4 * kg);
        f16x4 pk;
        pk[0] = (_Float16)fmaxf(acc[0] + bv.x, 0.f);
        pk[1] = (_Float16)fmaxf(acc[1] + bv.y, 0.f);
        pk[2] = (_Float16)fmaxf(acc[2] + bv.z, 0.f);
        pk[3] = (_Float16)fmaxf(acc[3] + bv.w, 0.f);
        *(f16x4*)&sh[57344 + rowloc * 264 + 64 * (win & 3) + 16 * (q & 3) + 4 * kg] = pk;
    };

    // y16 tail: K=368 at x col 1808 (chunk14 off 64B); chunks 14,15,16 -> slots 0,1,2
    auto y16comp = [&](int rh) {
        const _Float16* A = ws + 245760 + (q & 3) * 6144;
        const int rowloc = 16 * rh + r;
        f32x4 acc = {0.f, 0.f, 0.f, 0.f};
        #pragma unroll
        for (int kk = 0; kk < 12; ++kk) {
            int off32 = 16 + 32 * kk + 8 * kg;        // fp32 offset from chunk-14 base
            if (32 * kk + 8 * kg >= 368) off32 = 376; // sp>=368 -> zero weights
            int cc = off32 >> 7;                      // 0,1,2 -> chunks 14,15,16
            int slotb = cc * 16384;                   // (14+cc)%7 == cc
            int colb = (off32 & 127) * 4;
            f16x8 B  = bfrag(slotb, rowloc, colb);
            f16x8 Af = *(const f16x8*)(A + kk * 512 + l * 8);
            acc = MFMA16(Af, B, acc);
        }
        float4 bv = *(const float4*)(b16 + 16 * (q & 3) + 4 * kg);
        f16x4 pk;
        pk[0] = (_Float16)fmaxf(acc[0] + bv.x, 0.f);
        pk[1] = (_Float16)fmaxf(acc[1] + bv.y, 0.f);
        pk[2] = (_Float16)fmaxf(acc[2] + bv.z, 0.f);
        pk[3] = (_Float16)fmaxf(acc[3] + bv.w, 0.f);
        *(f16x4*)&sh[57344 + rowloc * 264 + 192 + 16 * (q & 3) + 4 * kg] = pk;
    };

    // layer-2 group g: waves 0..7 -> (rh=q>>2, t=4g+(q&3)); reads ygrp, writes zsm
    auto l2group = [&](int g) {
        if (q < 8) {
            int rh = q >> 2, t = 4 * g + (q & 3);
            const _Float16* A = ws + 270336 + t * 4096;
            f32x4 acc = {0.f, 0.f, 0.f, 0.f};
            #pragma unroll
            for (int kk = 0; kk < 8; ++kk) {
                f16x8 B  = *(const f16x8*)&sh[57344 + (16 * rh + r) * 264 + 32 * kk + 8 * kg];
                f16x8 Af = *(const f16x8*)(A + kk * 512 + l * 8);
                acc = MFMA16(Af, B, acc);
            }
            float4 bv = *(const float4*)(b2 + 16 * t + 4 * kg);
            f16x4 pk;
            pk[0] = (_Float16)fmaxf(acc[0] + bv.x, 0.f);
            pk[1] = (_Float16)fmaxf(acc[1] + bv.y, 0.f);
            pk[2] = (_Float16)fmaxf(acc[2] + bv.z, 0.f);
            pk[3] = (_Float16)fmaxf(acc[3] + bv.w, 0.f);
            *(f16x4*)&sh[65792 + (16 * rh + r) * 264 + 16 * t + 4 * kg] = pk;
        }
    };

    // ---- prologue: chunks 0..6 in flight (7 deep) ----
    issue(0); issue(1); issue(2); issue(3); issue(4); issue(5); issue(6);

    // ---- l1 passes (pairs) with interleaved group-wise l2 ----
    {
        int winh = q >> 3;             // 0/1: which window of the pair
        int rh   = (q >> 2) & 1;
        // pass 0 (wins 0,1)
        PASSTOP4();
        wincomp(0 + winh, rh, b1 + (0 + winh) * 64);
        // pass 1 (wins 2,3)
        PASSTOP2(); issue(7); issue(8);
        wincomp(2 + winh, rh, b1 + (2 + winh) * 64);
        BARL(); l2group(0);
        // pass 2 (wins 4,5)
        PASSTOP2(); issue(9); issue(10);
        wincomp(4 + winh, rh, b1 + (4 + winh) * 64);
        // pass 3 (wins 6,7)
        PASSTOP2(); issue(11); issue(12);
        wincomp(6 + winh, rh, b1 + (6 + winh) * 64);
        BARL(); l2group(1);
        // pass 4 (wins 8,9)
        PASSTOP2(); issue(13); issue(14);
        wincomp(8 + winh, rh, b1 + (8 + winh) * 64);
        // pass 5 (wins 10,11)
        PASSTOP2(); issue(15); issue(16);
        wincomp(10 + winh, rh, b1 + (10 + winh) * 64);
        BARL(); l2group(2);
        // pass 6 (wins 12,13)
        PASSTOP2();
        wincomp(12 + winh, rh, b1 + (12 + winh) * 64);
        // pass 7 (win 14 | y16)
        PASSTOP0();
        if (q < 8) wincomp(14, rh, b1 + 14 * 64);
        else       y16comp(rh);
        BARL(); l2group(3);
    }
    BARL();                                           // z complete

    // ---- layer 3: jobs (t, rh) over 17 tiles x 2 halves; pool -> ps (R13 text) ----
    {
        float* psp = (float*)sh;
        auto l3job = [&](int t, int rh2) {
            const _Float16* A = ws + 335872 + t * 4096;
            f32x4 acc = {0.f, 0.f, 0.f, 0.f};
            #pragma unroll
            for (int kk = 0; kk < 8; ++kk) {
                f16x8 B  = *(const f16x8*)&sh[65792 + (16 * rh2 + r) * 264 + 32 * kk + 8 * kg];
                f16x8 Af = *(const f16x8*)(A + kk * 512 + l * 8);
                acc = MFMA16(Af, B, acc);
            }
            float p[10];
            #pragma unroll
            for (int c = 0; c < 10; ++c) p[c] = 0.f;
            #pragma unroll
            for (int tt = 0; tt < 4; ++tt) {
                int o = 16 * t + 4 * kg + tt;
                if (o < 260) p[(unsigned)o / 26u] += fmaxf(acc[tt] + b3[o], 0.f);
            }
            #pragma unroll
            for (int c = 0; c < 10; ++c) {
                p[c] += __shfl_xor(p[c], 16);
                p[c] += __shfl_xor(p[c], 32);
            }
            if (kg == 0) {
                #pragma unroll
                for (int c = 0; c < 10; ++c)
                    psp[t * 320 + (16 * rh2 + r) * 10 + c] = p[c];
            }
        };
        l3job(q >> 1, q & 1);
        l3job((q + 16) >> 1, q & 1);
        if (q < 2) l3job(16, q);
    }
    BARL();                                           // ps in

    // ---- final: threads 0..31 = rows; sum 17 tiles; softmax; out ----
    if (tid < 32) {
        const float* psp = (const float*)sh;
        float v[10];
        #pragma unroll
        for (int c = 0; c < 10; ++c) {
            float s = 0.f;
            #pragma unroll
            for (int t = 0; t < 17; ++t) s += psp[t * 320 + tid * 10 + c];
            v[c] = s;
        }
        float mx = v[0];
        #pragma unroll
        for (int c = 1; c < 10; ++c) mx = fmaxf(mx, v[c]);
        float e[10], se = 0.f;
        #pragma unroll
        for (int c = 0; c < 10; ++c) { e[c] = expf(v[c] - mx); se += e[c]; }
        float inv = 1.f / se;
        float* orow = out + (size_t)(wg * 32 + tid) * 10;
        #pragma unroll
        for (int c = 0; c < 10; ++c) orow[c] = e[c] * inv;
    }
#undef PASSTOP4
#undef PASSTOP2
#undef PASSTOP0
#undef BARL
}

extern "C" void kernel_launch(void* const* d_in, const int* in_sizes, int n_in,
                              void* d_out, int out_size, void* d_ws, size_t ws_size,
                              hipStream_t stream)
{
    const float* x   = (const float*)d_in[0];
    const float* W1  = (const float*)d_in[1];
    const float* b1  = (const float*)d_in[2];
    const float* W16 = (const float*)d_in[3];
    const float* b16 = (const float*)d_in[4];
    const float* W2  = (const float*)d_in[5];
    const float* b2  = (const float*)d_in[6];
    const float* W3  = (const float*)d_in[7];
    const float* b3  = (const float*)d_in[8];
    float*    out = (float*)d_out;
    _Float16* ws  = (_Float16*)d_ws;

    tea_prep<<<1584, 256, 0, stream>>>(W1, W16, W2, W3, ws);
    tea_dma <<<512, 1024, 0, stream>>>(x, b1, b16, b2, b3, ws, out);
}

// Round 16
// 63.076 us; speedup vs baseline: 1.3967x; 1.3967x over previous
//
#include <hip/hip_runtime.h>
#include <cstdint>
#include <cstddef>

typedef _Float16 f16x8 __attribute__((ext_vector_type(8)));
typedef _Float16 f16x4 __attribute__((ext_vector_type(4)));
typedef float    f32x4 __attribute__((ext_vector_type(4)));

#define MFMA16(a,b,c) __builtin_amdgcn_mfma_f32_16x16x32_f16((a),(b),(c),0,0,0)

// ws layout (halfs) — weights in 16x16-MFMA fragment-linear order (R12/R13/R15-verified):
//   W1F  [15][4ot][8kk][64][8] @0       (245760)
//   W16F [4ot][12kk][64][8]    @245760  (24576)   sp=32kk+8(l>>4)+j; x col=1808+sp; zero sp<12 or sp>=368
//   W2F  [16t][8kk][64][8]     @270336  (65536)
//   W3F  [17t][8kk][64][8]     @335872  (69632)   o>=260 zero
__global__ void tea_prep(const float* __restrict__ W1, const float* __restrict__ W16,
                         const float* __restrict__ W2, const float* __restrict__ W3,
                         _Float16* __restrict__ ws)
{
    int i = blockIdx.x * blockDim.x + threadIdx.x;
    if (i < 245760) {
        int win = i >> 14, t = i & 16383;
        int ot = t >> 12, kk = (t >> 9) & 7, l = (t >> 3) & 63, j = t & 7;
        int o = 16 * ot + (l & 15);
        int s = 32 * kk + 8 * (l >> 4) + j;
        ws[i] = (_Float16)W1[(win * 256 + s) * 64 + o];
    } else if (i < 270336) {
        int t = i - 245760;
        int ot = t / 6144, t2 = t % 6144;
        int kk = t2 >> 9, l = (t2 >> 3) & 63, j = t2 & 7;
        int o = 16 * ot + (l & 15);
        int sp = 32 * kk + 8 * (l >> 4) + j;
        ws[i] = (_Float16)((sp >= 12 && sp < 368) ? W16[(sp - 12) * 64 + o] : 0.f);
    } else if (i < 335872) {
        int t = i - 270336;
        int q2 = t >> 12, kk = (t >> 9) & 7, l = (t >> 3) & 63, j = t & 7;
        int og = 16 * q2 + (l & 15);
        int g = q2 >> 2, o2 = og - 64 * g;
        int s = 32 * kk + 8 * (l >> 4) + j;
        ws[i] = (_Float16)W2[(g * 256 + s) * 64 + o2];
    } else if (i < 405504) {
        int t = i - 335872;
        int tt = t >> 12, kk = (t >> 9) & 7, l = (t >> 3) & 63, j = t & 7;
        int o = 16 * tt + (l & 15);
        int s = 32 * kk + 8 * (l >> 4) + j;
        ws[i] = (_Float16)((o < 260) ? W3[s * 260 + o] : 0.f);
    }
}

// Producer/consumer DMA-pipelined fused kernel.
// 512 blocks x 32 rows, 1024 threads (16 waves), 1 block/CU.
//   waves 8..15: producers — ONLY chunk DMA (pure vmcnt stream, counted waits work)
//   waves 0..7 : consumers — weight loads + MFMA (their vmcnt never touches DMAs)
// LDS sh[74240] halfs = 148480 B:
//   ring: 7 slots x [32 rows][512 B] fp32 chunks, bytes [0, 114688)
//         (source-XOR-swizzled: byte-in-row ^= (row&7)<<4, applied on DMA src AND reads)
//   ygrp: f16 [32][264], halfs [57344, 65792)   current group's y (4 windows x 64)
//   zsm : f16 [32][264], halfs [65792, 74240)
//   ps  : f32 [17][32][10], bytes [0, 21760)    alias ring (written in l3; ring dead)
// Ring schedule: pass p reads chunks 2p..2p+2; pass p issues 2p+5, 2p+6 whose slots
// ((2p-2)%7, (2p-1)%7) are provably dead at the pass-p barrier (fixes R15's race).
__global__ __launch_bounds__(1024, 4)
void tea_dma(const float* __restrict__ x,
             const float* __restrict__ b1,  const float* __restrict__ b16,
             const float* __restrict__ b2,  const float* __restrict__ b3,
             const _Float16* __restrict__ ws, float* __restrict__ out)
{
    __shared__ _Float16 sh[74240];
    char* shb = (char*)sh;

    const int tid = threadIdx.x;
    const int bid = blockIdx.x;
    const int wg  = (bid & 7) * 64 + (bid >> 3);      // bijective XCD swizzle (512%8==0)
    const int q = tid >> 6, l = tid & 63, r = l & 15, kg = l >> 4;
    const bool prod = (q >= 8);
    const int  pw   = q - 8;                          // producer wave id 0..7

    const char* xb = (const char*)(x + (size_t)wg * 32 * 2176);

    // producer: 2 instrs per chunk; wave pw covers rows 4pw..4pw+3
    auto issue = [&](int c) {
        #pragma unroll
        for (int i = 0; i < 2; ++i) {
            int row = 4 * pw + 2 * i + (l >> 5);
            int colphys = (l & 31) * 16;
            int collog = colphys ^ ((row & 7) << 4);  // inverse-swizzle the SOURCE
            const void* src = xb + (size_t)row * 8704 + (size_t)c * 512 + collog;
            void* dst = shb + (c % 7) * 16384 + (4 * pw + 2 * i) * 512;  // +lane*16 by HW
            __builtin_amdgcn_global_load_lds(
                (const __attribute__((address_space(1))) void*)src,
                (__attribute__((address_space(3))) void*)dst, 16, 0, 0);
        }
    };

    // pass top: producers prove old chunks delivered (counted), everyone syncs lgkm
#define PASSTOP(N) do { \
    if (prod) asm volatile("s_waitcnt vmcnt(" #N ")" ::: "memory"); \
    asm volatile("s_waitcnt lgkmcnt(0)" ::: "memory"); \
    __builtin_amdgcn_s_barrier(); \
    __builtin_amdgcn_sched_barrier(0); } while (0)
#define BARL() do { \
    asm volatile("s_waitcnt lgkmcnt(0)" ::: "memory"); \
    __builtin_amdgcn_s_barrier(); \
    __builtin_amdgcn_sched_barrier(0); } while (0)

    // B-frag from ring: 8 fp32 at (row, cols) of chunk in slotbyte (read-side XOR)
    auto bfrag = [&](int slotbyte, int rowloc, int colb) -> f16x8 {
        int swz = (rowloc & 7) << 4;
        f32x4 u = *(const f32x4*)(shb + slotbyte + rowloc * 512 + (colb ^ swz));
        f32x4 v = *(const f32x4*)(shb + slotbyte + rowloc * 512 + ((colb + 16) ^ swz));
        f16x8 B;
        B[0] = (_Float16)u[0]; B[1] = (_Float16)u[1]; B[2] = (_Float16)u[2]; B[3] = (_Float16)u[3];
        B[4] = (_Float16)v[0]; B[5] = (_Float16)v[1]; B[6] = (_Float16)v[2]; B[7] = (_Float16)v[3];
        return B;
    };

    // consumer window job: (win, ot=q&3), BOTH row-halves with one A-frag set
    auto wincomp2 = [&](int win, const float* bp) {
        const _Float16* A = ws + win * 16384 + (q & 3) * 4096;
        f16x8 Af[8];
        #pragma unroll
        for (int kk = 0; kk < 8; ++kk)
            Af[kk] = *(const f16x8*)(A + kk * 512 + l * 8);
        float4 bv = *(const float4*)(bp + 16 * (q & 3) + 4 * kg);
        #pragma unroll
        for (int rh = 0; rh < 2; ++rh) {
            const int rowloc = 16 * rh + r;
            f32x4 acc = {0.f, 0.f, 0.f, 0.f};
            #pragma unroll
            for (int kk = 0; kk < 8; ++kk) {
                int slotb = ((win + (kk >> 2)) % 7) * 16384;
                int colb = 128 * (kk & 3) + 32 * kg;
                acc = MFMA16(Af[kk], bfrag(slotb, rowloc, colb), acc);
            }
            f16x4 pk;
            pk[0] = (_Float16)fmaxf(acc[0] + bv.x, 0.f);
            pk[1] = (_Float16)fmaxf(acc[1] + bv.y, 0.f);
            pk[2] = (_Float16)fmaxf(acc[2] + bv.z, 0.f);
            pk[3] = (_Float16)fmaxf(acc[3] + bv.w, 0.f);
            *(f16x4*)&sh[57344 + rowloc * 264 + 64 * (win & 3) + 16 * (q & 3) + 4 * kg] = pk;
        }
    };

    // y16 tail (consumer): ot=q&3, rh given; chunks 14,15,16 -> slots 0,1,2
    auto y16comp = [&](int rh) {
        const _Float16* A = ws + 245760 + (q & 3) * 6144;
        const int rowloc = 16 * rh + r;
        f32x4 acc = {0.f, 0.f, 0.f, 0.f};
        #pragma unroll
        for (int kk = 0; kk < 12; ++kk) {
            int off32 = 16 + 32 * kk + 8 * kg;        // fp32 offset from chunk-14 base
            if (32 * kk + 8 * kg >= 368) off32 = 376; // sp>=368 -> zero weights
            int cc = off32 >> 7;                      // 0,1,2 -> chunks 14,15,16
            int slotb = cc * 16384;                   // (14+cc)%7 == cc
            int colb = (off32 & 127) * 4;
            f16x8 B  = bfrag(slotb, rowloc, colb);
            f16x8 Af = *(const f16x8*)(A + kk * 512 + l * 8);
            acc = MFMA16(Af, B, acc);
        }
        float4 bv = *(const float4*)(b16 + 16 * (q & 3) + 4 * kg);
        f16x4 pk;
        pk[0] = (_Float16)fmaxf(acc[0] + bv.x, 0.f);
        pk[1] = (_Float16)fmaxf(acc[1] + bv.y, 0.f);
        pk[2] = (_Float16)fmaxf(acc[2] + bv.z, 0.f);
        pk[3] = (_Float16)fmaxf(acc[3] + bv.w, 0.f);
        *(f16x4*)&sh[57344 + rowloc * 264 + 192 + 16 * (q & 3) + 4 * kg] = pk;
    };

    // layer-2 group g (consumers): (rh=q>>2, t=4g+(q&3)); reads ygrp, writes zsm
    auto l2group = [&](int g) {
        if (q < 8) {
            int rh = q >> 2, t = 4 * g + (q & 3);
            const _Float16* A = ws + 270336 + t * 4096;
            f32x4 acc = {0.f, 0.f, 0.f, 0.f};
            #pragma unroll
            for (int kk = 0; kk < 8; ++kk) {
                f16x8 B  = *(const f16x8*)&sh[57344 + (16 * rh + r) * 264 + 32 * kk + 8 * kg];
                f16x8 Af = *(const f16x8*)(A + kk * 512 + l * 8);
                acc = MFMA16(Af, B, acc);
            }
            float4 bv = *(const float4*)(b2 + 16 * t + 4 * kg);
            f16x4 pk;
            pk[0] = (_Float16)fmaxf(acc[0] + bv.x, 0.f);
            pk[1] = (_Float16)fmaxf(acc[1] + bv.y, 0.f);
            pk[2] = (_Float16)fmaxf(acc[2] + bv.z, 0.f);
            pk[3] = (_Float16)fmaxf(acc[3] + bv.w, 0.f);
            *(f16x4*)&sh[65792 + (16 * rh + r) * 264 + 16 * t + 4 * kg] = pk;
        }
    };

    // ---- prologue: producers put chunks 0..4 in flight ----
    if (prod) { issue(0); issue(1); issue(2); issue(3); issue(4); }

    // ---- l1 passes (window pairs); pass p reads chunks 2p..2p+2, issues 2p+5,2p+6 ----
    {
        // pass 0 (wins 0,1)
        PASSTOP(4);
        if (prod) { issue(5); issue(6); }
        else      wincomp2(0 + (q >> 2), b1 + (0 + (q >> 2)) * 64);
        // pass 1 (wins 2,3)
        PASSTOP(4);
        if (prod) { issue(7); issue(8); }
        else      wincomp2(2 + (q >> 2), b1 + (2 + (q >> 2)) * 64);
        BARL(); l2group(0);
        // pass 2 (wins 4,5)
        PASSTOP(4);
        if (prod) { issue(9); issue(10); }
        else      wincomp2(4 + (q >> 2), b1 + (4 + (q >> 2)) * 64);
        // pass 3 (wins 6,7)
        PASSTOP(4);
        if (prod) { issue(11); issue(12); }
        else      wincomp2(6 + (q >> 2), b1 + (6 + (q >> 2)) * 64);
        BARL(); l2group(1);
        // pass 4 (wins 8,9)
        PASSTOP(4);
        if (prod) { issue(13); issue(14); }
        else      wincomp2(8 + (q >> 2), b1 + (8 + (q >> 2)) * 64);
        // pass 5 (wins 10,11)
        PASSTOP(4);
        if (prod) { issue(15); issue(16); }
        else      wincomp2(10 + (q >> 2), b1 + (10 + (q >> 2)) * 64);
        BARL(); l2group(2);
        // pass 6 (wins 12,13)
        PASSTOP(4);
        if (!prod) wincomp2(12 + (q >> 2), b1 + (12 + (q >> 2)) * 64);
        // pass 7 (win 14 + y16): consumers do one win14 job and one y16 job each
        PASSTOP(0);
        if (!prod) {
            // win14: jobs (ot=q&3, rh=q>>2) — single-rh variant via wincomp on one half
            {
                const _Float16* A = ws + 14 * 16384 + (q & 3) * 4096;
                const int rh = q >> 2, rowloc = 16 * rh + r;
                f32x4 acc = {0.f, 0.f, 0.f, 0.f};
                #pragma unroll
                for (int kk = 0; kk < 8; ++kk) {
                    int slotb = ((14 + (kk >> 2)) % 7) * 16384;
                    int colb = 128 * (kk & 3) + 32 * kg;
                    f16x8 Af = *(const f16x8*)(A + kk * 512 + l * 8);
                    acc = MFMA16(Af, bfrag(slotb, rowloc, colb), acc);
                }
                float4 bv = *(const float4*)(b1 + 14 * 64 + 16 * (q & 3) + 4 * kg);
                f16x4 pk;
                pk[0] = (_Float16)fmaxf(acc[0] + bv.x, 0.f);
                pk[1] = (_Float16)fmaxf(acc[1] + bv.y, 0.f);
                pk[2] = (_Float16)fmaxf(acc[2] + bv.z, 0.f);
                pk[3] = (_Float16)fmaxf(acc[3] + bv.w, 0.f);
                *(f16x4*)&sh[57344 + rowloc * 264 + 64 * (14 & 3) + 16 * (q & 3) + 4 * kg] = pk;
            }
            y16comp(q >> 2);
        }
        BARL(); l2group(3);
    }
    BARL();                                           // z complete

    // ---- layer 3: all 16 waves; jobs (t, rh) over 17 tiles x 2 halves; pool -> ps ----
    {
        float* psp = (float*)sh;
        auto l3job = [&](int t, int rh2) {
            const _Float16* A = ws + 335872 + t * 4096;
            f32x4 acc = {0.f, 0.f, 0.f, 0.f};
            #pragma unroll
            for (int kk = 0; kk < 8; ++kk) {
                f16x8 B  = *(const f16x8*)&sh[65792 + (16 * rh2 + r) * 264 + 32 * kk + 8 * kg];
                f16x8 Af = *(const f16x8*)(A + kk * 512 + l * 8);
                acc = MFMA16(Af, B, acc);
            }
            float p[10];
            #pragma unroll
            for (int c = 0; c < 10; ++c) p[c] = 0.f;
            #pragma unroll
            for (int tt = 0; tt < 4; ++tt) {
                int o = 16 * t + 4 * kg + tt;
                if (o < 260) p[(unsigned)o / 26u] += fmaxf(acc[tt] + b3[o], 0.f);
            }
            #pragma unroll
            for (int c = 0; c < 10; ++c) {
                p[c] += __shfl_xor(p[c], 16);
                p[c] += __shfl_xor(p[c], 32);
            }
            if (kg == 0) {
                #pragma unroll
                for (int c = 0; c < 10; ++c)
                    psp[t * 320 + (16 * rh2 + r) * 10 + c] = p[c];
            }
        };
        l3job(q >> 1, q & 1);
        l3job((q + 16) >> 1, q & 1);
        if (q < 2) l3job(16, q);
    }
    BARL();                                           // ps in

    // ---- final: threads 0..31 = rows; sum 17 tiles; softmax; out ----
    if (tid < 32) {
        const float* psp = (const float*)sh;
        float v[10];
        #pragma unroll
        for (int c = 0; c < 10; ++c) {
            float s = 0.f;
            #pragma unroll
            for (int t = 0; t < 17; ++t) s += psp[t * 320 + tid * 10 + c];
            v[c] = s;
        }
        float mx = v[0];
        #pragma unroll
        for (int c = 1; c < 10; ++c) mx = fmaxf(mx, v[c]);
        float e[10], se = 0.f;
        #pragma unroll
        for (int c = 0; c < 10; ++c) { e[c] = expf(v[c] - mx); se += e[c]; }
        float inv = 1.f / se;
        float* orow = out + (size_t)(wg * 32 + tid) * 10;
        #pragma unroll
        for (int c = 0; c < 10; ++c) orow[c] = e[c] * inv;
    }
#undef PASSTOP
#undef BARL
}

extern "C" void kernel_launch(void* const* d_in, const int* in_sizes, int n_in,
                              void* d_out, int out_size, void* d_ws, size_t ws_size,
                              hipStream_t stream)
{
    const float* x   = (const float*)d_in[0];
    const float* W1  = (const float*)d_in[1];
    const float* b1  = (const float*)d_in[2];
    const float* W16 = (const float*)d_in[3];
    const float* b16 = (const float*)d_in[4];
    const float* W2  = (const float*)d_in[5];
    const float* b2  = (const float*)d_in[6];
    const float* W3  = (const float*)d_in[7];
    const float* b3  = (const float*)d_in[8];
    float*    out = (float*)d_out;
    _Float16* ws  = (_Float16*)d_ws;

    tea_prep<<<1584, 256, 0, stream>>>(W1, W16, W2, W3, ws);
    tea_dma <<<512, 1024, 0, stream>>>(x, b1, b16, b2, b3, ws, out);
}

// Round 17
// 62.352 us; speedup vs baseline: 1.4130x; 1.0116x over previous
//
#include <hip/hip_runtime.h>
#include <cstdint>
#include <cstddef>

typedef _Float16 f16x8 __attribute__((ext_vector_type(8)));
typedef _Float16 f16x4 __attribute__((ext_vector_type(4)));
typedef float    f32x4 __attribute__((ext_vector_type(4)));

#define MFMA16(a,b,c) __builtin_amdgcn_mfma_f32_16x16x32_f16((a),(b),(c),0,0,0)

// ws layout (halfs) — weights in 16x16-MFMA fragment-linear order (R12/R13/R15-verified):
//   W1F  [15][4ot][8kk][64][8] @0       (245760)
//   W16F [4ot][12kk][64][8]    @245760  (24576)   sp=32kk+8(l>>4)+j; x col=1808+sp; zero sp<12 or sp>=368
//   W2F  [16t][8kk][64][8]     @270336  (65536)
//   W3F  [17t][8kk][64][8]     @335872  (69632)   o>=260 zero
__global__ void tea_prep(const float* __restrict__ W1, const float* __restrict__ W16,
                         const float* __restrict__ W2, const float* __restrict__ W3,
                         _Float16* __restrict__ ws)
{
    int i = blockIdx.x * blockDim.x + threadIdx.x;
    if (i < 245760) {
        int win = i >> 14, t = i & 16383;
        int ot = t >> 12, kk = (t >> 9) & 7, l = (t >> 3) & 63, j = t & 7;
        int o = 16 * ot + (l & 15);
        int s = 32 * kk + 8 * (l >> 4) + j;
        ws[i] = (_Float16)W1[(win * 256 + s) * 64 + o];
    } else if (i < 270336) {
        int t = i - 245760;
        int ot = t / 6144, t2 = t % 6144;
        int kk = t2 >> 9, l = (t2 >> 3) & 63, j = t2 & 7;
        int o = 16 * ot + (l & 15);
        int sp = 32 * kk + 8 * (l >> 4) + j;
        ws[i] = (_Float16)((sp >= 12 && sp < 368) ? W16[(sp - 12) * 64 + o] : 0.f);
    } else if (i < 335872) {
        int t = i - 270336;
        int q2 = t >> 12, kk = (t >> 9) & 7, l = (t >> 3) & 63, j = t & 7;
        int og = 16 * q2 + (l & 15);
        int g = q2 >> 2, o2 = og - 64 * g;
        int s = 32 * kk + 8 * (l >> 4) + j;
        ws[i] = (_Float16)W2[(g * 256 + s) * 64 + o2];
    } else if (i < 405504) {
        int t = i - 335872;
        int tt = t >> 12, kk = (t >> 9) & 7, l = (t >> 3) & 63, j = t & 7;
        int o = 16 * tt + (l & 15);
        int s = 32 * kk + 8 * (l >> 4) + j;
        ws[i] = (_Float16)((o < 260) ? W3[s * 260 + o] : 0.f);
    }
}

// Producer/consumer DMA-pipelined fused kernel (R16 + consumer-path tuning:
// A-frag prefetch, rh-interleaved MFMA chains, setprio on MFMA cluster).
// 512 blocks x 32 rows, 1024 threads (16 waves), 1 block/CU.
//   waves 8..15: producers — ONLY chunk DMA (pure vmcnt stream, counted waits work)
//   waves 0..7 : consumers — weight loads + MFMA (their vmcnt never touches DMAs)
// LDS sh[74240] halfs = 148480 B:
//   ring: 7 slots x [32 rows][512 B] fp32 chunks, bytes [0, 114688)
//         (source-XOR-swizzled: byte-in-row ^= (row&7)<<4, applied on DMA src AND reads)
//   ygrp: f16 [32][264], halfs [57344, 65792)   current group's y (4 windows x 64)
//   zsm : f16 [32][264], halfs [65792, 74240)
//   ps  : f32 [17][32][10], bytes [0, 21760)    alias ring (written in l3; ring dead)
__global__ __launch_bounds__(1024, 4)
void tea_dma(const float* __restrict__ x,
             const float* __restrict__ b1,  const float* __restrict__ b16,
             const float* __restrict__ b2,  const float* __restrict__ b3,
             const _Float16* __restrict__ ws, float* __restrict__ out)
{
    __shared__ _Float16 sh[74240];
    char* shb = (char*)sh;

    const int tid = threadIdx.x;
    const int bid = blockIdx.x;
    const int wg  = (bid & 7) * 64 + (bid >> 3);      // bijective XCD swizzle (512%8==0)
    const int q = tid >> 6, l = tid & 63, r = l & 15, kg = l >> 4;
    const bool prod = (q >= 8);
    const int  pw   = q - 8;                          // producer wave id 0..7

    const char* xb = (const char*)(x + (size_t)wg * 32 * 2176);

    // producer: 2 instrs per chunk; wave pw covers rows 4pw..4pw+3
    auto issue = [&](int c) {
        #pragma unroll
        for (int i = 0; i < 2; ++i) {
            int row = 4 * pw + 2 * i + (l >> 5);
            int colphys = (l & 31) * 16;
            int collog = colphys ^ ((row & 7) << 4);  // inverse-swizzle the SOURCE
            const void* src = xb + (size_t)row * 8704 + (size_t)c * 512 + collog;
            void* dst = shb + (c % 7) * 16384 + (4 * pw + 2 * i) * 512;  // +lane*16 by HW
            __builtin_amdgcn_global_load_lds(
                (const __attribute__((address_space(1))) void*)src,
                (__attribute__((address_space(3))) void*)dst, 16, 0, 0);
        }
    };

    // pass top: producers prove old chunks delivered (counted), everyone syncs lgkm
#define PASSTOP(N) do { \
    if (prod) asm volatile("s_waitcnt vmcnt(" #N ")" ::: "memory"); \
    asm volatile("s_waitcnt lgkmcnt(0)" ::: "memory"); \
    __builtin_amdgcn_s_barrier(); \
    __builtin_amdgcn_sched_barrier(0); } while (0)
#define BARL() do { \
    asm volatile("s_waitcnt lgkmcnt(0)" ::: "memory"); \
    __builtin_amdgcn_s_barrier(); \
    __builtin_amdgcn_sched_barrier(0); } while (0)

    // B-frag from ring: 8 fp32 at (row, cols) of chunk in slotbyte (read-side XOR)
    auto bfrag = [&](int slotbyte, int rowloc, int colb) -> f16x8 {
        int swz = (rowloc & 7) << 4;
        f32x4 u = *(const f32x4*)(shb + slotbyte + rowloc * 512 + (colb ^ swz));
        f32x4 v = *(const f32x4*)(shb + slotbyte + rowloc * 512 + ((colb + 16) ^ swz));
        f16x8 B;
        B[0] = (_Float16)u[0]; B[1] = (_Float16)u[1]; B[2] = (_Float16)u[2]; B[3] = (_Float16)u[3];
        B[4] = (_Float16)v[0]; B[5] = (_Float16)v[1]; B[6] = (_Float16)v[2]; B[7] = (_Float16)v[3];
        return B;
    };

    // consumer: persistent A-fragment set, prefetched one pass ahead
    f16x8 Afn[8];
    if (!prod) {
        const _Float16* A0 = ws + (q >> 2) * 16384 + (q & 3) * 4096;
        #pragma unroll
        for (int kk = 0; kk < 8; ++kk)
            Afn[kk] = *(const f16x8*)(A0 + kk * 512 + l * 8);
    }

    // consumer window job: (win, ot=q&3), BOTH row-halves, rh chains interleaved;
    // uses prefetched Afn; reloads Afn for nextwin (if >=0) after the MFMA cluster.
    auto wincomp2 = [&](int win, const float* bp, int nextwin) {
        float4 bv = *(const float4*)(bp + 16 * (q & 3) + 4 * kg);
        f32x4 acc0 = {0.f, 0.f, 0.f, 0.f}, acc1 = {0.f, 0.f, 0.f, 0.f};
        __builtin_amdgcn_s_setprio(1);
        #pragma unroll
        for (int kk = 0; kk < 8; ++kk) {
            int slotb = ((win + (kk >> 2)) % 7) * 16384;
            int colb = 128 * (kk & 3) + 32 * kg;
            f16x8 B0 = bfrag(slotb, r, colb);
            f16x8 B1 = bfrag(slotb, 16 + r, colb);
            acc0 = MFMA16(Afn[kk], B0, acc0);
            acc1 = MFMA16(Afn[kk], B1, acc1);
        }
        __builtin_amdgcn_s_setprio(0);
        if (nextwin >= 0) {
            const _Float16* An = ws + nextwin * 16384 + (q & 3) * 4096;
            #pragma unroll
            for (int kk = 0; kk < 8; ++kk)
                Afn[kk] = *(const f16x8*)(An + kk * 512 + l * 8);
        }
        f16x4 pk0, pk1;
        pk0[0] = (_Float16)fmaxf(acc0[0] + bv.x, 0.f);
        pk0[1] = (_Float16)fmaxf(acc0[1] + bv.y, 0.f);
        pk0[2] = (_Float16)fmaxf(acc0[2] + bv.z, 0.f);
        pk0[3] = (_Float16)fmaxf(acc0[3] + bv.w, 0.f);
        pk1[0] = (_Float16)fmaxf(acc1[0] + bv.x, 0.f);
        pk1[1] = (_Float16)fmaxf(acc1[1] + bv.y, 0.f);
        pk1[2] = (_Float16)fmaxf(acc1[2] + bv.z, 0.f);
        pk1[3] = (_Float16)fmaxf(acc1[3] + bv.w, 0.f);
        *(f16x4*)&sh[57344 + r * 264 + 64 * (win & 3) + 16 * (q & 3) + 4 * kg] = pk0;
        *(f16x4*)&sh[57344 + (16 + r) * 264 + 64 * (win & 3) + 16 * (q & 3) + 4 * kg] = pk1;
    };

    // y16 tail (consumer): ot=q&3, rh given; chunks 14,15,16 -> slots 0,1,2
    auto y16comp = [&](int rh) {
        const _Float16* A = ws + 245760 + (q & 3) * 6144;
        const int rowloc = 16 * rh + r;
        f32x4 acc = {0.f, 0.f, 0.f, 0.f};
        #pragma unroll
        for (int kk = 0; kk < 12; ++kk) {
            int off32 = 16 + 32 * kk + 8 * kg;        // fp32 offset from chunk-14 base
            if (32 * kk + 8 * kg >= 368) off32 = 376; // sp>=368 -> zero weights
            int cc = off32 >> 7;                      // 0,1,2 -> chunks 14,15,16
            int slotb = cc * 16384;                   // (14+cc)%7 == cc
            int colb = (off32 & 127) * 4;
            f16x8 B  = bfrag(slotb, rowloc, colb);
            f16x8 Af = *(const f16x8*)(A + kk * 512 + l * 8);
            acc = MFMA16(Af, B, acc);
        }
        float4 bv = *(const float4*)(b16 + 16 * (q & 3) + 4 * kg);
        f16x4 pk;
        pk[0] = (_Float16)fmaxf(acc[0] + bv.x, 0.f);
        pk[1] = (_Float16)fmaxf(acc[1] + bv.y, 0.f);
        pk[2] = (_Float16)fmaxf(acc[2] + bv.z, 0.f);
        pk[3] = (_Float16)fmaxf(acc[3] + bv.w, 0.f);
        *(f16x4*)&sh[57344 + rowloc * 264 + 192 + 16 * (q & 3) + 4 * kg] = pk;
    };

    // layer-2 group g (consumers): (rh=q>>2, t=4g+(q&3)); reads ygrp, writes zsm
    auto l2group = [&](int g) {
        if (q < 8) {
            int rh = q >> 2, t = 4 * g + (q & 3);
            const _Float16* A = ws + 270336 + t * 4096;
            f32x4 acc = {0.f, 0.f, 0.f, 0.f};
            #pragma unroll
            for (int kk = 0; kk < 8; ++kk) {
                f16x8 B  = *(const f16x8*)&sh[57344 + (16 * rh + r) * 264 + 32 * kk + 8 * kg];
                f16x8 Af = *(const f16x8*)(A + kk * 512 + l * 8);
                acc = MFMA16(Af, B, acc);
            }
            float4 bv = *(const float4*)(b2 + 16 * t + 4 * kg);
            f16x4 pk;
            pk[0] = (_Float16)fmaxf(acc[0] + bv.x, 0.f);
            pk[1] = (_Float16)fmaxf(acc[1] + bv.y, 0.f);
            pk[2] = (_Float16)fmaxf(acc[2] + bv.z, 0.f);
            pk[3] = (_Float16)fmaxf(acc[3] + bv.w, 0.f);
            *(f16x4*)&sh[65792 + (16 * rh + r) * 264 + 16 * t + 4 * kg] = pk;
        }
    };

    // ---- prologue: producers put chunks 0..4 in flight ----
    if (prod) { issue(0); issue(1); issue(2); issue(3); issue(4); }

    // ---- l1 passes (window pairs); pass p reads chunks 2p..2p+2, issues 2p+5,2p+6 ----
    {
        const int wq = q >> 2;                        // consumer window-of-pair (0/1)
        // pass 0 (wins 0,1)
        PASSTOP(4);
        if (prod) { issue(5); issue(6); }
        else      wincomp2(0 + wq, b1 + (0 + wq) * 64, 2 + wq);
        // pass 1 (wins 2,3)
        PASSTOP(4);
        if (prod) { issue(7); issue(8); }
        else      wincomp2(2 + wq, b1 + (2 + wq) * 64, 4 + wq);
        BARL(); l2group(0);
        // pass 2 (wins 4,5)
        PASSTOP(4);
        if (prod) { issue(9); issue(10); }
        else      wincomp2(4 + wq, b1 + (4 + wq) * 64, 6 + wq);
        // pass 3 (wins 6,7)
        PASSTOP(4);
        if (prod) { issue(11); issue(12); }
        else      wincomp2(6 + wq, b1 + (6 + wq) * 64, 8 + wq);
        BARL(); l2group(1);
        // pass 4 (wins 8,9)
        PASSTOP(4);
        if (prod) { issue(13); issue(14); }
        else      wincomp2(8 + wq, b1 + (8 + wq) * 64, 10 + wq);
        // pass 5 (wins 10,11)
        PASSTOP(4);
        if (prod) { issue(15); issue(16); }
        else      wincomp2(10 + wq, b1 + (10 + wq) * 64, 12 + wq);
        BARL(); l2group(2);
        // pass 6 (wins 12,13)
        PASSTOP(4);
        if (!prod) wincomp2(12 + wq, b1 + (12 + wq) * 64, -1);
        // pass 7 (win 14 + y16): consumers do one win14 job and one y16 job each
        PASSTOP(0);
        if (!prod) {
            {
                const _Float16* A = ws + 14 * 16384 + (q & 3) * 4096;
                const int rh = q >> 2, rowloc = 16 * rh + r;
                f32x4 acc = {0.f, 0.f, 0.f, 0.f};
                #pragma unroll
                for (int kk = 0; kk < 8; ++kk) {
                    int slotb = ((14 + (kk >> 2)) % 7) * 16384;
                    int colb = 128 * (kk & 3) + 32 * kg;
                    f16x8 Af = *(const f16x8*)(A + kk * 512 + l * 8);
                    acc = MFMA16(Af, bfrag(slotb, rowloc, colb), acc);
                }
                float4 bv = *(const float4*)(b1 + 14 * 64 + 16 * (q & 3) + 4 * kg);
                f16x4 pk;
                pk[0] = (_Float16)fmaxf(acc[0] + bv.x, 0.f);
                pk[1] = (_Float16)fmaxf(acc[1] + bv.y, 0.f);
                pk[2] = (_Float16)fmaxf(acc[2] + bv.z, 0.f);
                pk[3] = (_Float16)fmaxf(acc[3] + bv.w, 0.f);
                *(f16x4*)&sh[57344 + rowloc * 264 + 64 * (14 & 3) + 16 * (q & 3) + 4 * kg] = pk;
            }
            y16comp(q >> 2);
        }
        BARL(); l2group(3);
    }
    BARL();                                           // z complete

    // ---- layer 3: all 16 waves; jobs (t, rh) over 17 tiles x 2 halves; pool -> ps ----
    {
        float* psp = (float*)sh;
        auto l3job = [&](int t, int rh2) {
            const _Float16* A = ws + 335872 + t * 4096;
            f32x4 acc = {0.f, 0.f, 0.f, 0.f};
            #pragma unroll
            for (int kk = 0; kk < 8; ++kk) {
                f16x8 B  = *(const f16x8*)&sh[65792 + (16 * rh2 + r) * 264 + 32 * kk + 8 * kg];
                f16x8 Af = *(const f16x8*)(A + kk * 512 + l * 8);
                acc = MFMA16(Af, B, acc);
            }
            float p[10];
            #pragma unroll
            for (int c = 0; c < 10; ++c) p[c] = 0.f;
            #pragma unroll
            for (int tt = 0; tt < 4; ++tt) {
                int o = 16 * t + 4 * kg + tt;
                if (o < 260) p[(unsigned)o / 26u] += fmaxf(acc[tt] + b3[o], 0.f);
            }
            #pragma unroll
            for (int c = 0; c < 10; ++c) {
                p[c] += __shfl_xor(p[c], 16);
                p[c] += __shfl_xor(p[c], 32);
            }
            if (kg == 0) {
                #pragma unroll
                for (int c = 0; c < 10; ++c)
                    psp[t * 320 + (16 * rh2 + r) * 10 + c] = p[c];
            }
        };
        l3job(q >> 1, q & 1);
        l3job((q + 16) >> 1, q & 1);
        if (q < 2) l3job(16, q);
    }
    BARL();                                           // ps in

    // ---- final: threads 0..31 = rows; sum 17 tiles; softmax; out ----
    if (tid < 32) {
        const float* psp = (const float*)sh;
        float v[10];
        #pragma unroll
        for (int c = 0; c < 10; ++c) {
            float s = 0.f;
            #pragma unroll
            for (int t = 0; t < 17; ++t) s += psp[t * 320 + tid * 10 + c];
            v[c] = s;
        }
        float mx = v[0];
        #pragma unroll
        for (int c = 1; c < 10; ++c) mx = fmaxf(mx, v[c]);
        float e[10], se = 0.f;
        #pragma unroll
        for (int c = 0; c < 10; ++c) { e[c] = expf(v[c] - mx); se += e[c]; }
        float inv = 1.f / se;
        float* orow = out + (size_t)(wg * 32 + tid) * 10;
        #pragma unroll
        for (int c = 0; c < 10; ++c) orow[c] = e[c] * inv;
    }
#undef PASSTOP
#undef BARL
}

extern "C" void kernel_launch(void* const* d_in, const int* in_sizes, int n_in,
                              void* d_out, int out_size, void* d_ws, size_t ws_size,
                              hipStream_t stream)
{
    const float* x   = (const float*)d_in[0];
    const float* W1  = (const float*)d_in[1];
    const float* b1  = (const float*)d_in[2];
    const float* W16 = (const float*)d_in[3];
    const float* b16 = (const float*)d_in[4];
    const float* W2  = (const float*)d_in[5];
    const float* b2  = (const float*)d_in[6];
    const float* W3  = (const float*)d_in[7];
    const float* b3  = (const float*)d_in[8];
    float*    out = (float*)d_out;
    _Float16* ws  = (_Float16*)d_ws;

    tea_prep<<<1584, 256, 0, stream>>>(W1, W16, W2, W3, ws);
    tea_dma <<<512, 1024, 0, stream>>>(x, b1, b16, b2, b3, ws, out);
}

// Round 18
// 51.176 us; speedup vs baseline: 1.7215x; 1.2184x over previous
//
#include <hip/hip_runtime.h>
#include <cstdint>
#include <cstddef>

typedef _Float16 f16x8 __attribute__((ext_vector_type(8)));
typedef _Float16 f16x4 __attribute__((ext_vector_type(4)));
typedef float    f32x4 __attribute__((ext_vector_type(4)));

#define MFMA16(a,b,c) __builtin_amdgcn_mfma_f32_16x16x32_f16((a),(b),(c),0,0,0)

// ws layout (halfs) — weights in 16x16-MFMA fragment-linear order (R12..R17-verified):
//   W1F  [15][4ot][8kk][64][8] @0       (245760)
//   W16F [4ot][12kk][64][8]    @245760  (24576)   sp=32kk+8(l>>4)+j; x col=1808+sp; zero sp<12 or sp>=368
//   W2F  [16t][8kk][64][8]     @270336  (65536)
//   W3F  [17t][8kk][64][8]     @335872  (69632)   o>=260 zero
__global__ void tea_prep(const float* __restrict__ W1, const float* __restrict__ W16,
                         const float* __restrict__ W2, const float* __restrict__ W3,
                         _Float16* __restrict__ ws)
{
    int i = blockIdx.x * blockDim.x + threadIdx.x;
    if (i < 245760) {
        int win = i >> 14, t = i & 16383;
        int ot = t >> 12, kk = (t >> 9) & 7, l = (t >> 3) & 63, j = t & 7;
        int o = 16 * ot + (l & 15);
        int s = 32 * kk + 8 * (l >> 4) + j;
        ws[i] = (_Float16)W1[(win * 256 + s) * 64 + o];
    } else if (i < 270336) {
        int t = i - 245760;
        int ot = t / 6144, t2 = t % 6144;
        int kk = t2 >> 9, l = (t2 >> 3) & 63, j = t2 & 7;
        int o = 16 * ot + (l & 15);
        int sp = 32 * kk + 8 * (l >> 4) + j;
        ws[i] = (_Float16)((sp >= 12 && sp < 368) ? W16[(sp - 12) * 64 + o] : 0.f);
    } else if (i < 335872) {
        int t = i - 270336;
        int q2 = t >> 12, kk = (t >> 9) & 7, l = (t >> 3) & 63, j = t & 7;
        int og = 16 * q2 + (l & 15);
        int g = q2 >> 2, o2 = og - 64 * g;
        int s = 32 * kk + 8 * (l >> 4) + j;
        ws[i] = (_Float16)W2[(g * 256 + s) * 64 + o2];
    } else if (i < 405504) {
        int t = i - 335872;
        int tt = t >> 12, kk = (t >> 9) & 7, l = (t >> 3) & 63, j = t & 7;
        int o = 16 * tt + (l & 15);
        int s = 32 * kk + 8 * (l >> 4) + j;
        ws[i] = (_Float16)((o < 260) ? W3[s * 260 + o] : 0.f);
    }
}

// Producer/consumer fused kernel, 64 rows/block, 256 blocks (1/CU, SINGLE generation).
//   waves 8..15: producers — x global->reg->cvt fp16->swizzled ds_write (ring)
//   waves 0..7 : consumers — weight frags + MFMA (x already fp16 in LDS)
// LDS sh[74752] halfs = 149504 B:
//   ring: 5 slots x [64 rows][256 B] fp16 chunks, bytes [0, 81920)
//         swizzle: byte-in-row ^= (row&15)<<4 (write AND read side)
//   ygrp: f16 [64][264], halfs [40960, 57856)   current group's y (4 wins x 64)
//   zsm : f16 [64][264], halfs [57856, 74752)
//   ps  : f32 [17][64][10], bytes [0, 43520)    alias ring (written in l3; ring dead)
// Ring schedule: prologue writes chunks 0-2; pass p reads 2p..2p+2, writes 2p+3,2p+4
// (slots mod 5 disjoint; chunk c's slot rewritten only 1+ passes after c's last read).
__global__ __launch_bounds__(1024, 4)
void tea_dma(const float* __restrict__ x,
             const float* __restrict__ b1,  const float* __restrict__ b16,
             const float* __restrict__ b2,  const float* __restrict__ b3,
             const _Float16* __restrict__ ws, float* __restrict__ out)
{
    __shared__ _Float16 sh[74752];
    char* shb = (char*)sh;

    const int tid = threadIdx.x;
    const int bid = blockIdx.x;
    const int wg  = (bid & 7) * 32 + (bid >> 3);      // bijective XCD swizzle (256%8==0)
    const int q = tid >> 6, l = tid & 63, r = l & 15, kg = l >> 4;
    const bool prod = (q >= 8);
    const int  pw   = q - 8;                          // producer wave id 0..7

    const float* xf = x + (size_t)wg * 64 * 2176;

    // ---- producer staging: double-buffered regs, one chunk-pair per pass ----
    float4 SE[4], SO[4];
    const int prow = 8 * pw + (l >> 3);               // lane's batch row (0..63)
    const int pcol = (l & 7) * 16;                    // lane's fp32 col base in chunk

    auto pload = [&](int c, float4* S) {
        const float* p = xf + (size_t)prow * 2176 + c * 128 + pcol;
        S[0] = *(const float4*)(p);
        S[1] = *(const float4*)(p + 4);
        S[2] = *(const float4*)(p + 8);
        S[3] = *(const float4*)(p + 12);
    };
    auto pwrite = [&](int c, float4* S) {
        const int swz  = (prow & 15) << 4;
        const int colb = pcol * 2;                    // byte offset of lane's 16 halfs
        char* base = shb + (c % 5) * 16384 + prow * 256;
        f16x8 h0, h1;
        h0[0]=(_Float16)S[0].x; h0[1]=(_Float16)S[0].y; h0[2]=(_Float16)S[0].z; h0[3]=(_Float16)S[0].w;
        h0[4]=(_Float16)S[1].x; h0[5]=(_Float16)S[1].y; h0[6]=(_Float16)S[1].z; h0[7]=(_Float16)S[1].w;
        h1[0]=(_Float16)S[2].x; h1[1]=(_Float16)S[2].y; h1[2]=(_Float16)S[2].z; h1[3]=(_Float16)S[2].w;
        h1[4]=(_Float16)S[3].x; h1[5]=(_Float16)S[3].y; h1[6]=(_Float16)S[3].z; h1[7]=(_Float16)S[3].w;
        *(f16x8*)(base + (colb ^ swz))        = h0;
        *(f16x8*)(base + ((colb + 16) ^ swz)) = h1;
    };

#define BARL() do { \
    asm volatile("s_waitcnt lgkmcnt(0)" ::: "memory"); \
    __builtin_amdgcn_s_barrier(); \
    __builtin_amdgcn_sched_barrier(0); } while (0)

    // ring B-frag (fp16): one ds_read_b128, read-side XOR matches pwrite's
    auto bfrag = [&](int slotb, int rowloc, int colb) -> f16x8 {
        int swz = (rowloc & 15) << 4;
        return *(const f16x8*)(shb + slotb + rowloc * 256 + (colb ^ swz));
    };

    // consumer: persistent A-fragment set, prefetched one pass ahead
    f16x8 Afn[8];
    const int wq = q >> 2;                            // consumer: window-of-pair (0/1)
    if (!prod) {
        const _Float16* A0 = ws + wq * 16384 + (q & 3) * 4096;
        #pragma unroll
        for (int kk = 0; kk < 8; ++kk)
            Afn[kk] = *(const f16x8*)(A0 + kk * 512 + l * 8);
    }

    auto ystore = [&](int rh, int winp, f32x4 a, float4 bv) {
        f16x4 pk;
        pk[0] = (_Float16)fmaxf(a[0] + bv.x, 0.f);
        pk[1] = (_Float16)fmaxf(a[1] + bv.y, 0.f);
        pk[2] = (_Float16)fmaxf(a[2] + bv.z, 0.f);
        pk[3] = (_Float16)fmaxf(a[3] + bv.w, 0.f);
        *(f16x4*)&sh[40960 + (16 * rh + r) * 264 + 64 * winp + 16 * (q & 3) + 4 * kg] = pk;
    };

    // consumer window job: (win, ot=q&3), ALL FOUR row-quarters interleaved
    auto wincomp = [&](int win, const float* bp, int nextwin) {
        float4 bv = *(const float4*)(bp + 16 * (q & 3) + 4 * kg);
        f32x4 a0 = {0.f,0.f,0.f,0.f}, a1 = a0, a2 = a0, a3 = a0;
        __builtin_amdgcn_s_setprio(1);
        #pragma unroll
        for (int kk = 0; kk < 8; ++kk) {
            int slotb = ((win + (kk >> 2)) % 5) * 16384;
            int colb  = 64 * (kk & 3) + 16 * kg;
            a0 = MFMA16(Afn[kk], bfrag(slotb,      r, colb), a0);
            a1 = MFMA16(Afn[kk], bfrag(slotb, 16 + r, colb), a1);
            a2 = MFMA16(Afn[kk], bfrag(slotb, 32 + r, colb), a2);
            a3 = MFMA16(Afn[kk], bfrag(slotb, 48 + r, colb), a3);
        }
        __builtin_amdgcn_s_setprio(0);
        if (nextwin >= 0) {
            const _Float16* An = ws + nextwin * 16384 + (q & 3) * 4096;
            #pragma unroll
            for (int kk = 0; kk < 8; ++kk)
                Afn[kk] = *(const f16x8*)(An + kk * 512 + l * 8);
        }
        ystore(0, win & 3, a0, bv);
        ystore(1, win & 3, a1, bv);
        ystore(2, win & 3, a2, bv);
        ystore(3, win & 3, a3, bv);
    };

    // win14 single row-quarter (pass 7); uses Afn prefetched with nextwin=14
    auto win14c = [&](int rh) {
        float4 bv = *(const float4*)(b1 + 14 * 64 + 16 * (q & 3) + 4 * kg);
        f32x4 acc = {0.f,0.f,0.f,0.f};
        #pragma unroll
        for (int kk = 0; kk < 8; ++kk) {
            int slotb = ((14 + (kk >> 2)) % 5) * 16384;
            int colb  = 64 * (kk & 3) + 16 * kg;
            acc = MFMA16(Afn[kk], bfrag(slotb, 16 * rh + r, colb), acc);
        }
        ystore(rh, 2, acc, bv);
    };

    // y16 tail: K=368 from x col 1808 (chunk-14 half-offset 16); chunks 14,15,16
    auto y16c = [&](int rh) {
        const _Float16* A = ws + 245760 + (q & 3) * 6144;
        f32x4 acc = {0.f,0.f,0.f,0.f};
        #pragma unroll
        for (int kk = 0; kk < 12; ++kk) {
            int offh = 16 + 32 * kk + 8 * kg;         // half-offset from chunk-14 base
            if (32 * kk + 8 * kg >= 368) offh = 376;  // sp>=368 -> zero weights
            int cc = offh >> 7;                       // 0,1,2 -> chunks 14,15,16
            int slotb = ((14 + cc) % 5) * 16384;      // slots 4,0,1
            int colb  = (offh & 127) * 2;
            f16x8 Af = *(const f16x8*)(A + kk * 512 + l * 8);
            acc = MFMA16(Af, bfrag(slotb, 16 * rh + r, colb), acc);
        }
        float4 bv = *(const float4*)(b16 + 16 * (q & 3) + 4 * kg);
        ystore(rh, 3, acc, bv);
    };

    // layer-2 group g (consumers): t = 4g+(q&3); row-quarters q>>2 and q>>2+2
    auto l2group = [&](int g) {
        if (q < 8) {
            int t = 4 * g + (q & 3);
            const _Float16* A = ws + 270336 + t * 4096;
            float4 bv = *(const float4*)(b2 + 16 * t + 4 * kg);
            #pragma unroll
            for (int rr = 0; rr < 2; ++rr) {
                int rh2 = (q >> 2) + 2 * rr;
                f32x4 acc = {0.f,0.f,0.f,0.f};
                #pragma unroll
                for (int kk = 0; kk < 8; ++kk) {
                    f16x8 B  = *(const f16x8*)&sh[40960 + (16 * rh2 + r) * 264 + 32 * kk + 8 * kg];
                    f16x8 Af = *(const f16x8*)(A + kk * 512 + l * 8);
                    acc = MFMA16(Af, B, acc);
                }
                f16x4 pk;
                pk[0] = (_Float16)fmaxf(acc[0] + bv.x, 0.f);
                pk[1] = (_Float16)fmaxf(acc[1] + bv.y, 0.f);
                pk[2] = (_Float16)fmaxf(acc[2] + bv.z, 0.f);
                pk[3] = (_Float16)fmaxf(acc[3] + bv.w, 0.f);
                *(f16x4*)&sh[57856 + (16 * rh2 + r) * 264 + 16 * t + 4 * kg] = pk;
            }
        }
    };

    // ---- prologue: chunks 0-2 staged; 3(SO),4(SE) in regs ----
    if (prod) {
        pload(0, SE); pload(1, SO);
        pwrite(0, SE); pwrite(1, SO);
        pload(2, SE); pload(3, SO);
        pwrite(2, SE);
        pload(4, SE);
    }

    // ---- l1: 8 passes (window pairs), l2 groups interleaved ----
    BARL();                                            // pass 0: chunks 0-2 ready
    if (prod) { pwrite(3, SO); pwrite(4, SE); pload(5, SO); pload(6, SE); }
    else      wincomp(wq, b1 + wq * 64, 2 + wq);
    BARL();                                            // pass 1
    if (prod) { pwrite(5, SO); pwrite(6, SE); pload(7, SO); pload(8, SE); }
    else      wincomp(2 + wq, b1 + (2 + wq) * 64, 4 + wq);
    BARL(); l2group(0);
    BARL();                                            // pass 2
    if (prod) { pwrite(7, SO); pwrite(8, SE); pload(9, SO); pload(10, SE); }
    else      wincomp(4 + wq, b1 + (4 + wq) * 64, 6 + wq);
    BARL();                                            // pass 3
    if (prod) { pwrite(9, SO); pwrite(10, SE); pload(11, SO); pload(12, SE); }
    else      wincomp(6 + wq, b1 + (6 + wq) * 64, 8 + wq);
    BARL(); l2group(1);
    BARL();                                            // pass 4
    if (prod) { pwrite(11, SO); pwrite(12, SE); pload(13, SO); pload(14, SE); }
    else      wincomp(8 + wq, b1 + (8 + wq) * 64, 10 + wq);
    BARL();                                            // pass 5
    if (prod) { pwrite(13, SO); pwrite(14, SE); pload(15, SO); pload(16, SE); }
    else      wincomp(10 + wq, b1 + (10 + wq) * 64, 12 + wq);
    BARL(); l2group(2);
    BARL();                                            // pass 6
    if (prod) { pwrite(15, SO); pwrite(16, SE); }
    else      wincomp(12 + wq, b1 + (12 + wq) * 64, 14);   // prefetch win14 A
    BARL();                                            // pass 7: chunks 14-16 ready
    if (!prod) {
        win14c(q >> 2); win14c(2 + (q >> 2));
        y16c(q >> 2);   y16c(2 + (q >> 2));
    }
    BARL(); l2group(3);
    BARL();                                            // z complete

    // ---- layer 3: all 16 waves; (t, rh2) jobs; pool -> ps (aliases dead ring) ----
    {
        float* psp = (float*)sh;
        auto l3job = [&](int t, int rh2) {
            const _Float16* A = ws + 335872 + t * 4096;
            f32x4 acc = {0.f,0.f,0.f,0.f};
            #pragma unroll
            for (int kk = 0; kk < 8; ++kk) {
                f16x8 B  = *(const f16x8*)&sh[57856 + (16 * rh2 + r) * 264 + 32 * kk + 8 * kg];
                f16x8 Af = *(const f16x8*)(A + kk * 512 + l * 8);
                acc = MFMA16(Af, B, acc);
            }
            float p[10];
            #pragma unroll
            for (int c = 0; c < 10; ++c) p[c] = 0.f;
            #pragma unroll
            for (int tt = 0; tt < 4; ++tt) {
                int o = 16 * t + 4 * kg + tt;
                if (o < 260) p[(unsigned)o / 26u] += fmaxf(acc[tt] + b3[o], 0.f);
            }
            #pragma unroll
            for (int c = 0; c < 10; ++c) {
                p[c] += __shfl_xor(p[c], 16);
                p[c] += __shfl_xor(p[c], 32);
            }
            if (kg == 0) {
                #pragma unroll
                for (int c = 0; c < 10; ++c)
                    psp[t * 640 + (16 * rh2 + r) * 10 + c] = p[c];
            }
        };
        l3job((q >> 2),      q & 3);
        l3job(4 + (q >> 2),  q & 3);
        l3job(8 + (q >> 2),  q & 3);
        l3job(12 + (q >> 2), q & 3);
        if (q < 4) l3job(16, q);
    }
    BARL();                                            // ps in

    // ---- final: threads 0..63 = rows; sum 17 tiles; softmax; out ----
    if (tid < 64) {
        const float* psp = (const float*)sh;
        float v[10];
        #pragma unroll
        for (int c = 0; c < 10; ++c) {
            float s = 0.f;
            #pragma unroll
            for (int t = 0; t < 17; ++t) s += psp[t * 640 + tid * 10 + c];
            v[c] = s;
        }
        float mx = v[0];
        #pragma unroll
        for (int c = 1; c < 10; ++c) mx = fmaxf(mx, v[c]);
        float e[10], se = 0.f;
        #pragma unroll
        for (int c = 0; c < 10; ++c) { e[c] = expf(v[c] - mx); se += e[c]; }
        float inv = 1.f / se;
        float* orow = out + (size_t)(wg * 64 + tid) * 10;
        #pragma unroll
        for (int c = 0; c < 10; ++c) orow[c] = e[c] * inv;
    }
#undef BARL
}

extern "C" void kernel_launch(void* const* d_in, const int* in_sizes, int n_in,
                              void* d_out, int out_size, void* d_ws, size_t ws_size,
                              hipStream_t stream)
{
    const float* x   = (const float*)d_in[0];
    const float* W1  = (const float*)d_in[1];
    const float* b1  = (const float*)d_in[2];
    const float* W16 = (const float*)d_in[3];
    const float* b16 = (const float*)d_in[4];
    const float* W2  = (const float*)d_in[5];
    const float* b2  = (const float*)d_in[6];
    const float* W3  = (const float*)d_in[7];
    const float* b3  = (const float*)d_in[8];
    float*    out = (float*)d_out;
    _Float16* ws  = (_Float16*)d_ws;

    tea_prep<<<1584, 256, 0, stream>>>(W1, W16, W2, W3, ws);
    tea_dma <<<256, 1024, 0, stream>>>(x, b1, b16, b2, b3, ws, out);
}